// Round 17
// baseline (125.067 us; speedup 1.0000x reference)
//
#include <hip/hip_runtime.h>
#include <hip/hip_bf16.h>

#define E_ 8
#define B_ 8
#define S_ 2048
#define D_ 512
#define R_ 128
#define M_TOT (B_ * S_)   // 16384

typedef __attribute__((ext_vector_type(8))) short bf16x8;
typedef __attribute__((ext_vector_type(4))) float f32x4;
typedef __attribute__((ext_vector_type(4))) short s16x4;

__device__ __forceinline__ void gload_lds16(void* lds, const void* g) {
  __builtin_amdgcn_global_load_lds(
      (const __attribute__((address_space(1))) void*)g,
      (__attribute__((address_space(3))) void*)lds, 16, 0, 0);
}

// ---------------------------------------------------------------------------
// Prep kernel: W only (x conversion folded into the GEMM's A-staging).
//   [0,32)      rotation: W[e] cols 0..128 (one-shot slab, R13-proven)
//   [32,2080)   W tail cols 129..511 = bf16(proj_w)
// ---------------------------------------------------------------------------
#define ROT_B 32
#define WT_B 2048
__global__ __launch_bounds__(256) void prep_w(
    const float* __restrict__ theta, const float* __restrict__ pw,
    __hip_bfloat16* __restrict__ Wb) {
  int blk = blockIdx.x;
  int t = threadIdx.x;
  if (blk < ROT_B) {
    __shared__ float cs[R_], ss[R_];
    __shared__ float Pch[128][130];
    __shared__ __hip_bfloat16 Wch[128][130];
    int e = blk >> 2;
    int r0 = (blk & 3) * 128;
    if (t < R_) {
      float a = tanhf(theta[e * R_ + t]) * 0.1f;
      cs[t] = cosf(a);
      ss[t] = sinf(a);
    }
    const float* Pe = pw + (size_t)e * D_ * D_;
    __hip_bfloat16* We = Wb + (size_t)e * D_ * D_;
#pragma unroll 8
    for (int it = 0; it < 64; ++it) {
      int row = it * 2 + (t >> 7);
      int col = t & 127;
      Pch[row][col] = Pe[(size_t)(r0 + row) * D_ + col];
    }
    if (t < 128) Pch[t][128] = Pe[(size_t)(r0 + t) * D_ + 128];
    __syncthreads();
    if (t < 128) {
      float u = Pch[t][0];
#pragma unroll 16
      for (int k = 0; k < R_; ++k) {
        float pj = Pch[t][k + 1];
        Wch[t][k + 1] = __float2bfloat16(cs[k] * pj - ss[k] * u);
        u = cs[k] * u + ss[k] * pj;
      }
      Wch[t][0] = __float2bfloat16(u);
    }
    __syncthreads();
#pragma unroll 8
    for (int it = 0; it < 64; ++it) {
      int row = it * 2 + (t >> 7);
      int col = t & 127;
      We[(size_t)(r0 + row) * D_ + col] = Wch[row][col];
    }
    if (t < 128) We[(size_t)(r0 + t) * D_ + 128] = Wch[t][128];
  } else {
    int g = (blk - ROT_B) * 256 + t;
    int gidx = g & 127;
    if (gidx < 32) return;
    float4 v = ((const float4*)pw)[g];
    union { short4 s; __hip_bfloat16 h[4]; } u;
    u.h[0] = __float2bfloat16(v.x);
    u.h[1] = __float2bfloat16(v.y);
    u.h[2] = __float2bfloat16(v.z);
    u.h[3] = __float2bfloat16(v.w);
    if (gidx > 32) {
      ((short4*)Wb)[g] = u.s;
    } else {
      Wb[(size_t)g * 4 + 1] = u.h[1];
      Wb[(size_t)g * 4 + 2] = u.h[2];
      Wb[(size_t)g * 4 + 3] = u.h[3];
    }
  }
}

// ---------------------------------------------------------------------------
// GEMM: out[e] = x @ Wb[e]^T, A read DIRECTLY as f32, converted in-kernel
// (kills the 96 MB xb round-trip + ~13us serial prep). Structure = R16:
// 256x128 block, 4 waves, BK=32, 2-buffer, 2 blocks/CU, XCD swizzle,
// swapped-operand MFMA, b128-staged full-line nt-store epilogue.
// Schedule per iter t: [wait B(t) vmcnt(10); lgkm; barrier; compute(t);
// lgkm; barrier; issue A(t+2)->regs + B(t+2) DMA; cvt+ds_write A(t+2)
// (clang inserts the vmcnt(12)-equivalent wait for the A regs)].
// A regs: single set, consumed in the same phase they return -> no parity.
// ---------------------------------------------------------------------------
__global__ __launch_bounds__(256, 2) void gemm_xw(
    const float* __restrict__ Xf,            // [M_TOT][512] f32
    const __hip_bfloat16* __restrict__ Wb,   // [E][512][512] rows=o, cols=d
    float* __restrict__ out)                 // [E][M_TOT][512]
{
  constexpr int BM = 256, BN = 128, BK = 32;
  constexpr int KD = D_, ND = D_;
  constexpr int NT = KD / BK;  // 16
  __shared__ __align__(16) char smem[49152];
  __hip_bfloat16 (*As)[BM * BK] =
      (__hip_bfloat16 (*)[BM * BK]) & smem[0];         // 2 x 16 KB
  __hip_bfloat16 (*Bs)[BN * BK] =
      (__hip_bfloat16 (*)[BN * BK]) & smem[32768];     // 2 x 8 KB
  float* Lep = (float*)&smem[0];                       // epilogue: 2x32x132 f32

  int bx = blockIdx.x;            // 2048 blocks
  int xcd = bx & 7, c = bx >> 3;  // chunk c in [0,256) per XCD
  int e = c >> 5;                 // 0..7  (e-major within XCD)
  int msub = (c >> 2) & 7;        // 0..7
  int nt = c & 3;                 // 0..3
  int mt = xcd * 8 + msub;        // 0..63

  int tid = threadIdx.x;
  int wave = tid >> 6, lane = tid & 63;
  int lr = lane & 15, lk = lane >> 4;
  int wm = wave >> 1, wn = wave & 1;   // 2x2 waves; wave-tile 128x64

  const float* Ag = Xf + (size_t)(mt * BM) * KD;
  const __hip_bfloat16* Bg = Wb + ((size_t)e * ND + (size_t)nt * BN) * KD;

  int srow = lane >> 2;
  int scol = (lane & 3) * 8;
  int arow = lane >> 3;
  int acol = (lane & 7) * 4;   // f32 elems

  int aoff = (wm * 128 + lr) * BK + lk * 8;
  int boff = (wn * 64 + lr) * BK + lk * 8;

  f32x4 acc[8][4];
#pragma unroll
  for (int i = 0; i < 8; ++i)
#pragma unroll
    for (int j = 0; j < 4; ++j) acc[i][j] = (f32x4){0.f, 0.f, 0.f, 0.f};

  // stage tile t's A (load f32 -> cvt -> ds_write b64) and B (DMA) into buf
#define ASTAGE(buf, t)                                                       \
  {                                                                          \
    f32x4 ar[8];                                                             \
    _Pragma("unroll") for (int j = 0; j < 8; ++j) {                          \
      int row = wave * 64 + j * 8 + arow;                                    \
      ar[j] = *(const f32x4*)(Ag + (size_t)row * KD + (t) * BK + acol);      \
    }                                                                        \
    _Pragma("unroll") for (int j = 0; j < 8; ++j) {                          \
      int row = wave * 64 + j * 8 + arow;                                    \
      union { s16x4 s; __hip_bfloat16 h[4]; } u;                             \
      u.h[0] = __float2bfloat16(ar[j].x);                                    \
      u.h[1] = __float2bfloat16(ar[j].y);                                    \
      u.h[2] = __float2bfloat16(ar[j].z);                                    \
      u.h[3] = __float2bfloat16(ar[j].w);                                    \
      *(s16x4*)&As[buf][row * BK + acol] = u.s;                              \
    }                                                                        \
  }
#define BLOAD(buf, t)                                                        \
  {                                                                          \
    _Pragma("unroll") for (int g = 0; g < 2; ++g) {                          \
      int rb = wave * 32 + g * 16;                                           \
      gload_lds16(&Bs[buf][rb * BK],                                         \
                  Bg + (size_t)(rb + srow) * KD + (t) * BK + scol);          \
    }                                                                        \
  }

  // prologue
  BLOAD(0, 0); BLOAD(1, 1);
  ASTAGE(0, 0);
  ASTAGE(1, 1);

#pragma unroll
  for (int t = 0; t < NT; ++t) {
    int buf = t & 1;
    // B(t) DMA visible (leave B(t+1)'s 2 in flight); A in LDS via lgkm
    if (t < NT - 1) {
      asm volatile("s_waitcnt vmcnt(2)" ::: "memory");
    } else {
      asm volatile("s_waitcnt vmcnt(0)" ::: "memory");
    }
    asm volatile("s_waitcnt lgkmcnt(0)" ::: "memory");
    __builtin_amdgcn_sched_barrier(0);
    __builtin_amdgcn_s_barrier();   // tile t visible to all 4 waves

    bf16x8 af[8], bfr[4];
#pragma unroll
    for (int ni = 0; ni < 4; ++ni)
      bfr[ni] = *(const bf16x8*)&Bs[buf][boff + ni * 16 * BK];
#pragma unroll
    for (int mi = 0; mi < 8; ++mi)
      af[mi] = *(const bf16x8*)&As[buf][aoff + mi * 16 * BK];
    __builtin_amdgcn_s_setprio(1);
#pragma unroll
    for (int mi = 0; mi < 8; ++mi)
#pragma unroll
      for (int ni = 0; ni < 4; ++ni)
        acc[mi][ni] = __builtin_amdgcn_mfma_f32_16x16x32_bf16(
            bfr[ni], af[mi], acc[mi][ni], 0, 0, 0);   // swapped (R15-proven)
    __builtin_amdgcn_s_setprio(0);

    // drain this tile's ds_reads before restaging over buf
    asm volatile("s_waitcnt lgkmcnt(0)" ::: "memory");
    __builtin_amdgcn_sched_barrier(0);
    __builtin_amdgcn_s_barrier();
    if (t + 2 < NT) {
      BLOAD(buf, t + 2);      // DMA issued first (stays in flight)
      ASTAGE(buf, t + 2);     // loads+cvt+write; clang waits only the A regs
    }
  }
#undef ASTAGE
#undef BLOAD

  // ---- write-coalesced epilogue: b128 staging + 512B-line nt stores ----
  size_t obase = (size_t)e * M_TOT * ND;
  int row0 = mt * BM;
  int col0 = nt * BN;
  float* Lh = Lep + (size_t)wm * (32 * 132);
#pragma unroll
  for (int r = 0; r < 4; ++r) {
#pragma unroll
    for (int m2 = 0; m2 < 2; ++m2) {
      int mi = 2 * r + m2;
#pragma unroll
      for (int ni = 0; ni < 4; ++ni)
        *(f32x4*)&Lh[(m2 * 16 + lr) * 132 + wn * 64 + ni * 16 + lk * 4] =
            acc[mi][ni];
    }
    __builtin_amdgcn_s_barrier();
#pragma unroll
    for (int j = 0; j < 8; ++j) {
      int lrow = wn * 16 + j * 2 + (lane >> 5);
      int lc4 = lane & 31;
      f32x4 v = *(const f32x4*)&Lh[lrow * 132 + lc4 * 4];
      int grow = row0 + wm * 128 + r * 32 + lrow;
      __builtin_nontemporal_store(
          v, (f32x4*)&out[obase + (size_t)grow * ND + col0 + lc4 * 4]);
    }
    __builtin_amdgcn_s_barrier();
  }
}

extern "C" void kernel_launch(void* const* d_in, const int* in_sizes, int n_in,
                              void* d_out, int out_size, void* d_ws, size_t ws_size,
                              hipStream_t stream) {
  const float* x = (const float*)d_in[0];        // [B][S][D] f32
  const float* theta = (const float*)d_in[1];    // [E][R] f32
  const float* proj_w = (const float*)d_in[2];   // [E][D][D] f32
  float* out = (float*)d_out;                    // [E][B][S][D] f32

  __hip_bfloat16* Wb = (__hip_bfloat16*)d_ws;    // 4 MB

  hipLaunchKernelGGL(prep_w, dim3(ROT_B + WT_B), dim3(256), 0,
                     stream, theta, proj_w, Wb);
  // grid: (M_TOT/256)=64 mt  x  8 e  x  (512/128)=4 nt  = 2048 blocks
  hipLaunchKernelGGL(gemm_xw, dim3(2048), dim3(256), 0, stream, x, Wb, out);
}